// Round 10
// baseline (438.961 us; speedup 1.0000x reference)
//
#include <hip/hip_runtime.h>
#include <hip/hip_fp8.h>

#define LOGZERO -4290774016.0f   // -(65504^2), exactly representable in fp32
#define L2E 1.4426950408889634f  // log2(e)
#define LN2 0.6931471805599453f

constexpr int Bb = 32, Tt = 512, Dd = 512, Vv = 4096;
constexpr int BT = Bb * Tt;

typedef __attribute__((ext_vector_type(4))) float f32x4;
typedef __attribute__((ext_vector_type(2))) long i64x2;
typedef long i64;

#define GLOBAL_AS __attribute__((address_space(1)))
#define LDS_AS    __attribute__((address_space(3)))

__device__ __forceinline__ float fexp2(float x) { return __builtin_amdgcn_exp2f(x); }  // 2^x
__device__ __forceinline__ float flog2(float x) { return __builtin_amdgcn_logf(x); }   // log2(x)

// pack 4 floats (scaled) -> 4 OCP e4m3 bytes
__device__ __forceinline__ unsigned cvt4_fp8(float4 v, float s) {
#if __has_builtin(__builtin_amdgcn_cvt_pk_fp8_f32)
  int p = __builtin_amdgcn_cvt_pk_fp8_f32(v.x * s, v.y * s, 0, false);
  p = __builtin_amdgcn_cvt_pk_fp8_f32(v.z * s, v.w * s, p, true);
  return (unsigned)p;
#else
  unsigned b0 = __hip_cvt_float_to_fp8(v.x * s, __HIP_SATFINITE, __HIP_E4M3);
  unsigned b1 = __hip_cvt_float_to_fp8(v.y * s, __HIP_SATFINITE, __HIP_E4M3);
  unsigned b2 = __hip_cvt_float_to_fp8(v.z * s, __HIP_SATFINITE, __HIP_E4M3);
  unsigned b3 = __hip_cvt_float_to_fp8(v.w * s, __HIP_SATFINITE, __HIP_E4M3);
  return b0 | (b1 << 8) | (b2 << 16) | (b3 << 24);
#endif
}

// logaddexp in the log2 domain
__device__ __forceinline__ float lg2add(float a, float b) {
  float mx = fmaxf(a, b);
  float d  = fabsf(a - b);
  return mx + flog2(1.0f + fexp2(-d));
}

// ---- kPre: pack x and W into fp8 FRAGMENT-ORDER layouts + zero counters ----
// Xfp layout (per 128-row tileM, 64 KB): byte16-slot t16 = (ks*4+rtp)*64+lane,
//   bytes = { x[tM*128+rtp*32+ln15][ks*32+quad*8 ..+8], same row +16 }.
// Wp layout (per cb=64-col block): slot = ((cb*16+ks)*2+ctp)*64+lane,
//   bytes = { W[cb*64+ctp*32+ln15][ks*32+quad*8 ..+8]*16, same row +16 }.
__global__ __launch_bounds__(256) void kPre(const float* __restrict__ x,
                                            const float* __restrict__ W,
                                            unsigned char* __restrict__ Xfp,
                                            unsigned char* __restrict__ Wp,
                                            int* __restrict__ cnt) {
  const int blk = blockIdx.x, tid = threadIdx.x;
  const int t = blk * 256 + tid;
  if (blk < 2048) {                     // Xfp: t = 0..524287
    int lane = t & 63, rtp = (t >> 6) & 3, ks = (t >> 8) & 15, tM = t >> 12;
    int ln15 = lane & 15, quad = lane >> 4;
    const float* p0 = x + (size_t)(tM * 128 + rtp * 32 + ln15) * Dd + ks * 32 + quad * 8;
    const float* p1 = p0 + 16 * Dd;
    uint4 o;
    o.x = cvt4_fp8(*(const float4*)p0, 1.0f);
    o.y = cvt4_fp8(*(const float4*)(p0 + 4), 1.0f);
    o.z = cvt4_fp8(*(const float4*)p1, 1.0f);
    o.w = cvt4_fp8(*(const float4*)(p1 + 4), 1.0f);
    *(uint4*)(Xfp + (size_t)t * 16) = o;
  } else if (blk < 2560) {              // Wp: tt = 0..131071
    int tt = t - 2048 * 256;
    int lane = tt & 63, ctp = (tt >> 6) & 1, ks = (tt >> 7) & 15, cb = tt >> 11;
    int ln15 = lane & 15, quad = lane >> 4;
    const float* p0 = W + (size_t)(cb * 64 + ctp * 32 + ln15) * Dd + ks * 32 + quad * 8;
    const float* p1 = p0 + 16 * Dd;
    uint4 o;
    o.x = cvt4_fp8(*(const float4*)p0, 16.0f);   // x16 prescale into e4m3 range
    o.y = cvt4_fp8(*(const float4*)(p0 + 4), 16.0f);
    o.z = cvt4_fp8(*(const float4*)p1, 16.0f);
    o.w = cvt4_fp8(*(const float4*)(p1 + 4), 16.0f);
    *(uint4*)(Wp + (size_t)tt * 16) = o;
  } else {
    if (tid < 32) cnt[tid] = 0;
  }
}

// ---- fused fp8 GEMM + exp-sum + beam scatter + (last-block-per-b) CTC DP ----
// grid 2048, 256 threads (4 waves). Block = 128 rows x 256 cols, full K=512.
// A staged once via fully-linear 1KB DMA bursts (packed layout -> conflict-free
// ds_read_b128); B = 2 contiguous-1KB dwordx4 loads/k-step, depth-1 prefetch,
// zero K-loop barriers. Partial exp-sums -> Spart[tileN] (no atomics). The
// 64th block finishing a given b runs the CTC DP for that b inline.
__global__ __launch_bounds__(256, 2) void kA(const unsigned char* __restrict__ Xfp,
                                             const unsigned char* __restrict__ Wp,
                                             const float* __restrict__ bias,
                                             const int* __restrict__ beam,
                                             const int* __restrict__ blankp,
                                             const int* __restrict__ eosp,
                                             const int* __restrict__ xl,
                                             float* __restrict__ Spart,
                                             float* __restrict__ selL,
                                             int* __restrict__ cnt,
                                             float* __restrict__ out,
                                             int Ly, int CB) {
  __shared__ unsigned char Ald[65536];   // union: packed A tile | sl[512*31] floats
  __shared__ float Spw[4][128];
  __shared__ float lgS[Tt], lastP1[Tt], blankLp[Tt];
  __shared__ int   selv[31];
  __shared__ float selb[31];
  __shared__ int   flagLds;

  const int tid = threadIdx.x;
  const int tileN = blockIdx.x & 15;
  const int tileM = blockIdx.x >> 4;
  const int row0 = tileM * 128, col0 = tileN * 256;
  const int bb = row0 >> 9;              // batch of this block
  const int lane = tid & 63, w = tid >> 6;
  const int ln15 = lane & 15, quad = lane >> 4;

  if (tid < 31) {
    int v = (tid == 0) ? *blankp : beam[bb * CB + tid - 1];
    selv[tid] = v;
    selb[tid] = bias[v];
  }

  // stage packed A tile: 64 x 1KB fully-linear DMA bursts
  const unsigned char* src = Xfp + (size_t)tileM * 65536;
  #pragma unroll
  for (int i = 0; i < 16; ++i) {
    int off = (w * 16 + i) * 1024;
    __builtin_amdgcn_global_load_lds((const GLOBAL_AS void*)(src + off + lane * 16),
                                     (LDS_AS void*)(Ald + off), 16, 0, 0);
  }
  __syncthreads();

  const int colw = col0 + w * 64;
  const int cb = tileN * 4 + w;
  f32x4 acc[4][8];
  #pragma unroll
  for (int ct = 0; ct < 4; ++ct)
    #pragma unroll
    for (int rt = 0; rt < 8; ++rt) acc[ct][rt] = {0.f, 0.f, 0.f, 0.f};

  const unsigned char* wpB = Wp + (size_t)cb * 32768 + lane * 16;
  i64x2 bc[2];
  bc[0] = *(const i64x2*)(wpB);
  bc[1] = *(const i64x2*)(wpB + 1024);

  for (int ks = 0; ks < 16; ++ks) {
    i64x2 af[4];
    #pragma unroll
    for (int rtp = 0; rtp < 4; ++rtp)
      af[rtp] = *(const i64x2*)&Ald[(ks * 4 + rtp) * 1024 + lane * 16];  // linear b128
    i64x2 bn[2];
    int ks2 = (ks < 15) ? (ks + 1) : 15;   // depth-1 B prefetch
    bn[0] = *(const i64x2*)(wpB + ks2 * 2048);
    bn[1] = *(const i64x2*)(wpB + ks2 * 2048 + 1024);
    #pragma unroll
    for (int ct = 0; ct < 4; ++ct)
      #pragma unroll
      for (int rt = 0; rt < 8; ++rt)
        acc[ct][rt] = __builtin_amdgcn_mfma_f32_16x16x32_fp8_fp8(
            af[rt >> 1][rt & 1], bc[ct >> 1][ct & 1], acc[ct][rt], 0, 0, 0);
    bc[0] = bn[0]; bc[1] = bn[1];
  }

  // epilogue 1: row-wise sum(exp(logit+bias)) -> per-block partial (no atomics)
  // col(ct) = colw + (ct>>1)*32 + (ct&1)*16 + ln15
  // row(rt,r) = row0 + (rt>>1)*32 + (rt&1)*16 + quad*4 + r
  float bvl[4];
  #pragma unroll
  for (int ct = 0; ct < 4; ++ct)
    bvl[ct] = bias[colw + (ct >> 1) * 32 + (ct & 1) * 16 + ln15] * L2E;
  const float SC = 0.0625f * L2E;        // undo W x16 prescale, ln->log2

  #pragma unroll
  for (int rt = 0; rt < 8; ++rt) {
    #pragma unroll
    for (int r = 0; r < 4; ++r) {
      float s = 0.f;
      #pragma unroll
      for (int ct = 0; ct < 4; ++ct) s += fexp2(acc[ct][rt][r] * SC + bvl[ct]);
      s += __shfl_xor(s, 1, 64);
      s += __shfl_xor(s, 2, 64);
      s += __shfl_xor(s, 4, 64);
      s += __shfl_xor(s, 8, 64);
      if (ln15 == 0)
        Spw[w][(rt >> 1) * 32 + (rt & 1) * 16 + quad * 4 + r] = s;
    }
  }
  __syncthreads();
  if (tid < 128) {
    float p = Spw[0][tid] + Spw[1][tid] + Spw[2][tid] + Spw[3][tid];
    Spart[(size_t)tileN * BT + row0 + tid] = p;
  }

  // epilogue 2: beam-column scatter (raw ln-domain logit + bias)
  const int tbase = row0 & 511;
  #pragma unroll
  for (int ct = 0; ct < 4; ++ct) {
    for (int s = 0; s < 31; ++s) {
      int local = selv[s] - colw - (ct >> 1) * 32 - (ct & 1) * 16;
      if (local >= 0 && local < 16 && ln15 == local) {
        float bvs = selb[s];
        #pragma unroll
        for (int rt = 0; rt < 8; ++rt)
          #pragma unroll
          for (int r = 0; r < 4; ++r) {
            int t = tbase + (rt >> 1) * 32 + (rt & 1) * 16 + quad * 4 + r;
            selL[((size_t)bb * Tt + t) * 31 + s] = acc[ct][rt][r] * 0.0625f + bvs;
          }
      }
    }
  }

  // ---- release + per-b counter: last of the 64 blocks for bb runs the DP ----
  __threadfence();
  __syncthreads();
  if (tid == 0) {
    int old = atomicAdd(&cnt[bb], 1);
    flagLds = (old == 63);
  }
  __syncthreads();
  if (!flagLds) return;
  __threadfence();                       // acquire side

  // ================= CTC DP + output assembly (one block per b) =============
  float* sl = (float*)Ald;               // reuse A-tile LDS: 512*31 floats
  for (int i = tid; i < Tt * 31; i += 256)
    sl[i] = selL[(size_t)bb * Tt * 31 + i] * L2E;
  for (int tt = tid; tt < Tt; tt += 256) {
    float s = 0.f;
    #pragma unroll
    for (int n = 0; n < 16; ++n) s += Spart[(size_t)n * BT + bb * Tt + tt];
    lgS[tt] = flog2(s);
  }
  __syncthreads();

  float* orow = out + (size_t)bb * Vv;
  for (int i = tid; i < Vv; i += 256) orow[i] = LOGZERO;

  const int xlb = xl[bb];
  float curP = LOGZERO;
  if (tid < 64) {
    const int ln = tid;
    float vloc[8];
    float run = 0.f;
    #pragma unroll
    for (int u = 0; u < 8; ++u) {
      int t = ln * 8 + u;
      float bl = sl[t * 31] - lgS[t];
      blankLp[t] = bl;
      run += bl;
      vloc[u] = run;
    }
    float inc = run;
    #pragma unroll
    for (int off = 1; off < 64; off <<= 1) {
      float o = __shfl_up(inc, off, 64);
      if (ln >= off) inc += o;
    }
    float excl = inc - run;
    #pragma unroll
    for (int u = 0; u < 8; ++u) lastP1[ln * 8 + u] = vloc[u] + excl;

    const int kk = (ln < CB) ? ln : (CB - 1);
    const float LOG2ZERO = LOGZERO * L2E;
    float Pn = LOG2ZERO, Pb = LOG2ZERO;
    float mrun = -3.0e38f, srun = 0.0f;
    int start = (Ly < Tt - 1) ? Ly : (Tt - 1);
    if (start == 0) {
      Pn = sl[1 + kk] - lgS[0];
      float vv = (0 < xlb) ? lg2add(Pn, Pb) : LOG2ZERO;
      float nm = fmaxf(mrun, vv);
      srun = srun * fexp2(mrun - nm) + fexp2(vv - nm);
      mrun = nm;
    }
    int t0 = (start > 1) ? start : 1;
    #pragma unroll 2
    for (int t = t0; t < Tt; ++t) {
      float xn = sl[t * 31 + 1 + kk] - lgS[t];
      float xb = blankLp[t];
      float pref = lastP1[t - 1];        // lastPsum == lastP1 bit-exactly
      float Pn2 = lg2add(Pn, pref) + xn;
      float Pb2 = lg2add(Pn, Pb) + xb;
      Pn = Pn2; Pb = Pb2;
      float vv = (t < xlb) ? lg2add(Pn, Pb) : LOG2ZERO;
      float nm = fmaxf(mrun, vv);
      srun = srun * fexp2(mrun - nm) + fexp2(vv - nm);
      mrun = nm;
    }
    curP = (mrun + flog2(srun)) * LN2;   // back to ln domain
  }
  __syncthreads();

  if (tid < 64) {
    if (tid < CB) orow[beam[bb * CB + tid]] = curP;
  }
  __syncthreads();
  if (tid == 0) {
    float eosv = (xlb >= 1) ? lastP1[xlb - 1] * LN2 : 0.0f;
    orow[*eosp] = eosv;
    orow[*blankp] = LOGZERO;
  }
}

extern "C" void kernel_launch(void* const* d_in, const int* in_sizes, int n_in,
                              void* d_out, int out_size, void* d_ws, size_t ws_size,
                              hipStream_t stream) {
  (void)n_in; (void)out_size; (void)ws_size;
  const float* x    = (const float*)d_in[0];
  const float* W    = (const float*)d_in[1];
  const float* bias = (const float*)d_in[2];
  const int* xl     = (const int*)d_in[3];
  const int* beam   = (const int*)d_in[5];
  const int* blankp = (const int*)d_in[6];
  const int* eosp   = (const int*)d_in[7];
  const int Ly = in_sizes[4] / Bb;
  const int CB = in_sizes[5] / Bb;

  float* Spart = (float*)d_ws;                                            // 1 MB
  float* selL  = (float*)((char*)d_ws + (size_t)0x100000);                // 2.03 MB
  int*   cnt   = (int*)((char*)d_ws + (size_t)0x300000);                  // 128 B
  unsigned char* Xfp = (unsigned char*)((char*)d_ws + (size_t)0x400000);  // 8 MB
  unsigned char* Wp  = (unsigned char*)((char*)d_ws + (size_t)0xC00000);  // 2 MB
  float* outf = (float*)d_out;

  kPre<<<2561, 256, 0, stream>>>(x, W, Xfp, Wp, cnt);
  kA<<<2048, 256, 0, stream>>>(Xfp, Wp, bias, beam, blankp, eosp, xl,
                               Spart, selL, cnt, outf, Ly, CB);
}

// Round 11
// 241.047 us; speedup vs baseline: 1.8211x; 1.8211x over previous
//
#include <hip/hip_runtime.h>
#include <hip/hip_fp8.h>

#define LOGZERO -4290774016.0f   // -(65504^2), exactly representable in fp32
#define L2E 1.4426950408889634f  // log2(e)
#define LN2 0.6931471805599453f

constexpr int Bb = 32, Tt = 512, Dd = 512, Vv = 4096;
constexpr int BT = Bb * Tt;

typedef __attribute__((ext_vector_type(4))) float f32x4;
typedef __attribute__((ext_vector_type(2))) long i64x2;
typedef long i64;

#define GLOBAL_AS __attribute__((address_space(1)))
#define LDS_AS    __attribute__((address_space(3)))

__device__ __forceinline__ float fexp2(float x) { return __builtin_amdgcn_exp2f(x); }  // 2^x
__device__ __forceinline__ float flog2(float x) { return __builtin_amdgcn_logf(x); }   // log2(x)

// pack 4 floats (scaled) -> 4 OCP e4m3 bytes
__device__ __forceinline__ unsigned cvt4_fp8(float4 v, float s) {
#if __has_builtin(__builtin_amdgcn_cvt_pk_fp8_f32)
  int p = __builtin_amdgcn_cvt_pk_fp8_f32(v.x * s, v.y * s, 0, false);
  p = __builtin_amdgcn_cvt_pk_fp8_f32(v.z * s, v.w * s, p, true);
  return (unsigned)p;
#else
  unsigned b0 = __hip_cvt_float_to_fp8(v.x * s, __HIP_SATFINITE, __HIP_E4M3);
  unsigned b1 = __hip_cvt_float_to_fp8(v.y * s, __HIP_SATFINITE, __HIP_E4M3);
  unsigned b2 = __hip_cvt_float_to_fp8(v.z * s, __HIP_SATFINITE, __HIP_E4M3);
  unsigned b3 = __hip_cvt_float_to_fp8(v.w * s, __HIP_SATFINITE, __HIP_E4M3);
  return b0 | (b1 << 8) | (b2 << 16) | (b3 << 24);
#endif
}

// logaddexp in the log2 domain
__device__ __forceinline__ float lg2add(float a, float b) {
  float mx = fmaxf(a, b);
  float d  = fabsf(a - b);
  return mx + flog2(1.0f + fexp2(-d));
}

// ---- kPre: pack x and W into fp8 FRAGMENT-ORDER layouts ----
// Xfp (per 128-row tileM, 64 KB): slot t16 = (ks*4+rtp)*64+lane,
//   bytes = { x[tM*128+rtp*32+ln15][ks*32+quad*8 ..+8], same row +16 }.
// Wp (per cb=64-col block, 32 KB): slot = ((cb*16+ks)*2+ctp)*64+lane,
//   bytes = { W[cb*64+ctp*32+ln15][ks*32+quad*8 ..+8]*16, same row +16 }.
__global__ __launch_bounds__(256) void kPre(const float* __restrict__ x,
                                            const float* __restrict__ W,
                                            unsigned char* __restrict__ Xfp,
                                            unsigned char* __restrict__ Wp) {
  const int blk = blockIdx.x, tid = threadIdx.x;
  const int t = blk * 256 + tid;
  if (blk < 2048) {                     // Xfp: t = 0..524287
    int lane = t & 63, rtp = (t >> 6) & 3, ks = (t >> 8) & 15, tM = t >> 12;
    int ln15 = lane & 15, quad = lane >> 4;
    const float* p0 = x + (size_t)(tM * 128 + rtp * 32 + ln15) * Dd + ks * 32 + quad * 8;
    const float* p1 = p0 + 16 * Dd;
    uint4 o;
    o.x = cvt4_fp8(*(const float4*)p0, 1.0f);
    o.y = cvt4_fp8(*(const float4*)(p0 + 4), 1.0f);
    o.z = cvt4_fp8(*(const float4*)p1, 1.0f);
    o.w = cvt4_fp8(*(const float4*)(p1 + 4), 1.0f);
    *(uint4*)(Xfp + (size_t)t * 16) = o;
  } else {                              // Wp: tt = 0..131071
    int tt = t - 2048 * 256;
    int lane = tt & 63, ctp = (tt >> 6) & 1, ks = (tt >> 7) & 15, cb = tt >> 11;
    int ln15 = lane & 15, quad = lane >> 4;
    const float* p0 = W + (size_t)(cb * 64 + ctp * 32 + ln15) * Dd + ks * 32 + quad * 8;
    const float* p1 = p0 + 16 * Dd;
    uint4 o;
    o.x = cvt4_fp8(*(const float4*)p0, 16.0f);   // x16 prescale into e4m3 range
    o.y = cvt4_fp8(*(const float4*)(p0 + 4), 16.0f);
    o.z = cvt4_fp8(*(const float4*)p1, 16.0f);
    o.w = cvt4_fp8(*(const float4*)(p1 + 4), 16.0f);
    *(uint4*)(Wp + (size_t)tt * 16) = o;
  }
}

// ---- barrier-free fp8 GEMM + exp-sum partials + beam scatter ----
// grid 2048, 256 threads (4 waves). Block = 128 rows x 256 cols, full K=512.
// A staged once via fully-linear 1KB DMA bursts (packed layout -> conflict-free
// ds_read_b128); B = 2 contiguous dwordx4 loads/k-step, depth-1 prefetch,
// zero K-loop barriers. Row exp-sums -> Spart[tileN] slice (no atomics).
__global__ __launch_bounds__(256, 2) void kA(const unsigned char* __restrict__ Xfp,
                                             const unsigned char* __restrict__ Wp,
                                             const float* __restrict__ bias,
                                             const int* __restrict__ beam,
                                             const int* __restrict__ blankp,
                                             float* __restrict__ Spart,
                                             float* __restrict__ selL,
                                             int CB) {
  __shared__ unsigned char Ald[65536];   // packed A tile
  __shared__ float Spw[4][128];
  __shared__ int   selv[31];
  __shared__ float selb[31];

  const int tid = threadIdx.x;
  const int tileN = blockIdx.x & 15;
  const int tileM = blockIdx.x >> 4;
  const int row0 = tileM * 128, col0 = tileN * 256;
  const int bb = row0 >> 9;              // batch of this block
  const int lane = tid & 63, w = tid >> 6;
  const int ln15 = lane & 15, quad = lane >> 4;

  if (tid < 31) {
    int v = (tid == 0) ? *blankp : beam[bb * CB + tid - 1];
    selv[tid] = v;
    selb[tid] = bias[v];
  }

  // stage packed A tile: 64 x 1KB fully-linear DMA bursts
  const unsigned char* src = Xfp + (size_t)tileM * 65536;
  #pragma unroll
  for (int i = 0; i < 16; ++i) {
    int off = (w * 16 + i) * 1024;
    __builtin_amdgcn_global_load_lds((const GLOBAL_AS void*)(src + off + lane * 16),
                                     (LDS_AS void*)(Ald + off), 16, 0, 0);
  }
  __syncthreads();                       // only barrier before epilogue

  const int colw = col0 + w * 64;
  const int cb = tileN * 4 + w;
  f32x4 acc[4][8];
  #pragma unroll
  for (int ct = 0; ct < 4; ++ct)
    #pragma unroll
    for (int rt = 0; rt < 8; ++rt) acc[ct][rt] = {0.f, 0.f, 0.f, 0.f};

  const unsigned char* wpB = Wp + (size_t)cb * 32768 + lane * 16;
  i64x2 bc[2];
  bc[0] = *(const i64x2*)(wpB);
  bc[1] = *(const i64x2*)(wpB + 1024);

  #pragma unroll 2
  for (int ks = 0; ks < 16; ++ks) {
    i64x2 af[4];
    #pragma unroll
    for (int rtp = 0; rtp < 4; ++rtp)
      af[rtp] = *(const i64x2*)&Ald[(ks * 4 + rtp) * 1024 + lane * 16];  // linear b128
    i64x2 bn[2];
    int ks2 = (ks < 15) ? (ks + 1) : 15;   // depth-1 B prefetch
    bn[0] = *(const i64x2*)(wpB + ks2 * 2048);
    bn[1] = *(const i64x2*)(wpB + ks2 * 2048 + 1024);
    #pragma unroll
    for (int ct = 0; ct < 4; ++ct)
      #pragma unroll
      for (int rt = 0; rt < 8; ++rt)
        acc[ct][rt] = __builtin_amdgcn_mfma_f32_16x16x32_fp8_fp8(
            af[rt >> 1][rt & 1], bc[ct >> 1][ct & 1], acc[ct][rt], 0, 0, 0);
    bc[0] = bn[0]; bc[1] = bn[1];
  }

  // epilogue 1: row-wise sum(exp(logit+bias)) -> per-block partial (no atomics)
  // col(ct) = colw + (ct>>1)*32 + (ct&1)*16 + ln15
  // row(rt,r) = row0 + (rt>>1)*32 + (rt&1)*16 + quad*4 + r
  float bvl[4];
  #pragma unroll
  for (int ct = 0; ct < 4; ++ct)
    bvl[ct] = bias[colw + (ct >> 1) * 32 + (ct & 1) * 16 + ln15] * L2E;
  const float SC = 0.0625f * L2E;        // undo W x16 prescale, ln->log2

  #pragma unroll
  for (int rt = 0; rt < 8; ++rt) {
    #pragma unroll
    for (int r = 0; r < 4; ++r) {
      float s = 0.f;
      #pragma unroll
      for (int ct = 0; ct < 4; ++ct) s += fexp2(acc[ct][rt][r] * SC + bvl[ct]);
      s += __shfl_xor(s, 1, 64);
      s += __shfl_xor(s, 2, 64);
      s += __shfl_xor(s, 4, 64);
      s += __shfl_xor(s, 8, 64);
      if (ln15 == 0)
        Spw[w][(rt >> 1) * 32 + (rt & 1) * 16 + quad * 4 + r] = s;
    }
  }
  __syncthreads();
  if (tid < 128) {
    float p = Spw[0][tid] + Spw[1][tid] + Spw[2][tid] + Spw[3][tid];
    Spart[(size_t)tileN * BT + row0 + tid] = p;
  }

  // epilogue 2: beam-column scatter (raw ln-domain logit + bias)
  const int tbase = row0 & 511;
  #pragma unroll
  for (int ct = 0; ct < 4; ++ct) {
    for (int s = 0; s < 31; ++s) {
      int local = selv[s] - colw - (ct >> 1) * 32 - (ct & 1) * 16;
      if (local >= 0 && local < 16 && ln15 == local) {
        float bvs = selb[s];
        #pragma unroll
        for (int rt = 0; rt < 8; ++rt)
          #pragma unroll
          for (int r = 0; r < 4; ++r) {
            int t = tbase + (rt >> 1) * 32 + (rt & 1) * 16 + quad * 4 + r;
            selL[((size_t)bb * Tt + t) * 31 + s] = acc[ct][rt][r] * 0.0625f + bvs;
          }
      }
    }
  }
}

// ---- CTC DP + output assembly, log2 domain. grid: B blocks x 256 threads ----
__global__ __launch_bounds__(256) void kC(const float* __restrict__ selL,
                                          const float* __restrict__ Spart,
                                          const int* __restrict__ xl,
                                          const int* __restrict__ beam,
                                          const int* __restrict__ blankp,
                                          const int* __restrict__ eosp,
                                          float* __restrict__ out,
                                          int Ly, int CB) {
  __shared__ float sl[Tt * 31];     // raw logits * log2(e)
  __shared__ float lgS[Tt];         // log2(sum_exp)
  __shared__ float lastP1[Tt];      // log2-domain blank cumsum
  __shared__ float blankLp[Tt];     // log2-domain blank logp
  const int b = blockIdx.x, tid = threadIdx.x;

  for (int i = tid; i < Tt * 31; i += 256)
    sl[i] = selL[(size_t)b * Tt * 31 + i] * L2E;
  for (int tt = tid; tt < Tt; tt += 256) {
    float s = 0.f;
    #pragma unroll
    for (int n = 0; n < 16; ++n) s += Spart[(size_t)n * BT + b * Tt + tt];
    lgS[tt] = flog2(s);
  }
  __syncthreads();

  float* orow = out + (size_t)b * Vv;
  for (int i = tid; i < Vv; i += 256) orow[i] = LOGZERO;

  const int xlb = xl[b];
  float curP = LOGZERO;
  if (tid < 64) {
    const int lane = tid;
    float vloc[8];
    float run = 0.f;
    #pragma unroll
    for (int u = 0; u < 8; ++u) {
      int t = lane * 8 + u;
      float bl = sl[t * 31] - lgS[t];
      blankLp[t] = bl;
      run += bl;
      vloc[u] = run;
    }
    float inc = run;
    #pragma unroll
    for (int off = 1; off < 64; off <<= 1) {
      float o = __shfl_up(inc, off, 64);
      if (lane >= off) inc += o;
    }
    float excl = inc - run;
    #pragma unroll
    for (int u = 0; u < 8; ++u) lastP1[lane * 8 + u] = vloc[u] + excl;

    const int kk = (lane < CB) ? lane : (CB - 1);
    const float LOG2ZERO = LOGZERO * L2E;
    float Pn = LOG2ZERO, Pb = LOG2ZERO;
    float mrun = -3.0e38f, srun = 0.0f;
    int start = (Ly < Tt - 1) ? Ly : (Tt - 1);
    if (start == 0) {
      Pn = sl[1 + kk] - lgS[0];
      float vv = (0 < xlb) ? lg2add(Pn, Pb) : LOG2ZERO;
      float nm = fmaxf(mrun, vv);
      srun = srun * fexp2(mrun - nm) + fexp2(vv - nm);
      mrun = nm;
    }
    int t0 = (start > 1) ? start : 1;
    #pragma unroll 2
    for (int t = t0; t < Tt; ++t) {
      float xn = sl[t * 31 + 1 + kk] - lgS[t];
      float xb = blankLp[t];
      float pref = lastP1[t - 1];   // lastPsum == lastP1 bit-exactly
      float Pn2 = lg2add(Pn, pref) + xn;
      float Pb2 = lg2add(Pn, Pb) + xb;
      Pn = Pn2; Pb = Pb2;
      float vv = (t < xlb) ? lg2add(Pn, Pb) : LOG2ZERO;   // off critical path
      float nm = fmaxf(mrun, vv);
      srun = srun * fexp2(mrun - nm) + fexp2(vv - nm);
      mrun = nm;
    }
    curP = (mrun + flog2(srun)) * LN2;       // back to ln domain
  }
  __syncthreads();   // LOGZERO fill + lastP1 complete

  if (tid < 64) {
    if (tid < CB) orow[beam[b * CB + tid]] = curP;
  }
  __syncthreads();
  if (tid == 0) {
    float eosv = (xlb >= 1) ? lastP1[xlb - 1] * LN2 : 0.0f;
    orow[*eosp] = eosv;
    orow[*blankp] = LOGZERO;
  }
}

extern "C" void kernel_launch(void* const* d_in, const int* in_sizes, int n_in,
                              void* d_out, int out_size, void* d_ws, size_t ws_size,
                              hipStream_t stream) {
  (void)n_in; (void)out_size; (void)ws_size;
  const float* x    = (const float*)d_in[0];
  const float* W    = (const float*)d_in[1];
  const float* bias = (const float*)d_in[2];
  const int* xl     = (const int*)d_in[3];
  const int* beam   = (const int*)d_in[5];
  const int* blankp = (const int*)d_in[6];
  const int* eosp   = (const int*)d_in[7];
  const int Ly = in_sizes[4] / Bb;
  const int CB = in_sizes[5] / Bb;

  float* Spart = (float*)d_ws;                                            // 1 MB
  float* selL  = (float*)((char*)d_ws + (size_t)0x100000);                // 2.03 MB
  unsigned char* Xfp = (unsigned char*)((char*)d_ws + (size_t)0x400000);  // 8 MB
  unsigned char* Wp  = (unsigned char*)((char*)d_ws + (size_t)0xC00000);  // 2 MB
  float* outf = (float*)d_out;

  kPre<<<2560, 256, 0, stream>>>(x, W, Xfp, Wp);
  kA<<<2048, 256, 0, stream>>>(Xfp, Wp, bias, beam, blankp, Spart, selL, CB);
  kC<<<Bb, 256, 0, stream>>>(selL, Spart, xl, beam, blankp, eosp, outf, Ly, CB);
}

// Round 12
// 223.909 us; speedup vs baseline: 1.9604x; 1.0765x over previous
//
#include <hip/hip_runtime.h>
#include <hip/hip_fp8.h>

#define LOGZERO -4290774016.0f   // -(65504^2), exactly representable in fp32
#define L2E 1.4426950408889634f  // log2(e)
#define LN2 0.6931471805599453f

constexpr int Bb = 32, Tt = 512, Dd = 512, Vv = 4096;
constexpr int BT = Bb * Tt;

typedef __attribute__((ext_vector_type(4))) float f32x4;
typedef __attribute__((ext_vector_type(2))) long i64x2;
typedef long i64;

#define GLOBAL_AS __attribute__((address_space(1)))
#define LDS_AS    __attribute__((address_space(3)))

__device__ __forceinline__ float fexp2(float x) { return __builtin_amdgcn_exp2f(x); }  // 2^x
__device__ __forceinline__ float flog2(float x) { return __builtin_amdgcn_logf(x); }   // log2(x)

// pack 4 floats (scaled) -> 4 OCP e4m3 bytes
__device__ __forceinline__ unsigned cvt4_fp8(float4 v, float s) {
#if __has_builtin(__builtin_amdgcn_cvt_pk_fp8_f32)
  int p = __builtin_amdgcn_cvt_pk_fp8_f32(v.x * s, v.y * s, 0, false);
  p = __builtin_amdgcn_cvt_pk_fp8_f32(v.z * s, v.w * s, p, true);
  return (unsigned)p;
#else
  unsigned b0 = __hip_cvt_float_to_fp8(v.x * s, __HIP_SATFINITE, __HIP_E4M3);
  unsigned b1 = __hip_cvt_float_to_fp8(v.y * s, __HIP_SATFINITE, __HIP_E4M3);
  unsigned b2 = __hip_cvt_float_to_fp8(v.z * s, __HIP_SATFINITE, __HIP_E4M3);
  unsigned b3 = __hip_cvt_float_to_fp8(v.w * s, __HIP_SATFINITE, __HIP_E4M3);
  return b0 | (b1 << 8) | (b2 << 16) | (b3 << 24);
#endif
}

// logaddexp in the log2 domain
__device__ __forceinline__ float lg2add(float a, float b) {
  float mx = fmaxf(a, b);
  float d  = fabsf(a - b);
  return mx + flog2(1.0f + fexp2(-d));
}

// ---- kPre: pack x and W into fp8 FRAGMENT-ORDER layouts ----
// Xfp (per 64-row tileM, 32 KB): slot t16 = tM*2048 + (ks*2+rtp)*64 + lane,
//   bytes = { x[tM*64+rtp*32+ln15][ks*32+quad*8 ..+8], same row +16 }.
// Wp (per cb=64-col block, 32 KB): slot = ((cb*16+ks)*2+ctp)*64+lane,
//   bytes = { W[cb*64+ctp*32+ln15][ks*32+quad*8 ..+8]*16, same row +16 }.
__global__ __launch_bounds__(256) void kPre(const float* __restrict__ x,
                                            const float* __restrict__ W,
                                            unsigned char* __restrict__ Xfp,
                                            unsigned char* __restrict__ Wp) {
  const int blk = blockIdx.x, tid = threadIdx.x;
  const int t = blk * 256 + tid;
  if (blk < 2048) {                     // Xfp: t = 0..524287
    int lane = t & 63, rtp = (t >> 6) & 1, ks = (t >> 7) & 15, tM = t >> 11;
    int ln15 = lane & 15, quad = lane >> 4;
    const float* p0 = x + (size_t)(tM * 64 + rtp * 32 + ln15) * Dd + ks * 32 + quad * 8;
    const float* p1 = p0 + 16 * Dd;
    uint4 o;
    o.x = cvt4_fp8(*(const float4*)p0, 1.0f);
    o.y = cvt4_fp8(*(const float4*)(p0 + 4), 1.0f);
    o.z = cvt4_fp8(*(const float4*)p1, 1.0f);
    o.w = cvt4_fp8(*(const float4*)(p1 + 4), 1.0f);
    *(uint4*)(Xfp + (size_t)t * 16) = o;
  } else {                              // Wp: tt = 0..131071
    int tt = t - 2048 * 256;
    int lane = tt & 63, ctp = (tt >> 6) & 1, ks = (tt >> 7) & 15, cb = tt >> 11;
    int ln15 = lane & 15, quad = lane >> 4;
    const float* p0 = W + (size_t)(cb * 64 + ctp * 32 + ln15) * Dd + ks * 32 + quad * 8;
    const float* p1 = p0 + 16 * Dd;
    uint4 o;
    o.x = cvt4_fp8(*(const float4*)p0, 16.0f);   // x16 prescale into e4m3 range
    o.y = cvt4_fp8(*(const float4*)(p0 + 4), 16.0f);
    o.z = cvt4_fp8(*(const float4*)p1, 16.0f);
    o.w = cvt4_fp8(*(const float4*)(p1 + 4), 16.0f);
    *(uint4*)(Wp + (size_t)tt * 16) = o;
  }
}

// ---- barrier-free fp8 GEMM + exp-sum partials + beam scatter, M_tile=64 ----
// grid 4096, 256 threads (4 waves). Block = 64 rows x 256 cols, full K=512.
// A = 32 KB packed LDS (linear 1KB DMA bursts, conflict-free ds_read_b128);
// B = 2 contiguous dwordx4 loads/k-step, depth-1 prefetch, zero K-loop
// barriers. 3 blocks/CU (launch_bounds cap) -> 3 waves/SIMD latency cover.
__global__ __launch_bounds__(256, 3) void kA(const unsigned char* __restrict__ Xfp,
                                             const unsigned char* __restrict__ Wp,
                                             const float* __restrict__ bias,
                                             const int* __restrict__ beam,
                                             const int* __restrict__ blankp,
                                             float* __restrict__ Spart,
                                             float* __restrict__ selL,
                                             int CB) {
  __shared__ unsigned char Ald[32768];   // packed A tile (64 rows x 512 K)
  __shared__ float Spw[4][64];
  __shared__ int   selv[31];
  __shared__ float selb[31];

  const int tid = threadIdx.x;
  const int tileN = blockIdx.x & 15;
  const int tileM = blockIdx.x >> 4;
  const int row0 = tileM * 64, col0 = tileN * 256;
  const int bb = row0 >> 9;              // batch of this block (64 | 512)
  const int lane = tid & 63, w = tid >> 6;
  const int ln15 = lane & 15, quad = lane >> 4;

  if (tid < 31) {
    int v = (tid == 0) ? *blankp : beam[bb * CB + tid - 1];
    selv[tid] = v;
    selb[tid] = bias[v];
  }

  // stage packed A tile: 32 x 1KB fully-linear DMA bursts (wave w does 8)
  const unsigned char* src = Xfp + (size_t)tileM * 32768;
  #pragma unroll
  for (int i = 0; i < 8; ++i) {
    int off = (w * 8 + i) * 1024;
    __builtin_amdgcn_global_load_lds((const GLOBAL_AS void*)(src + off + lane * 16),
                                     (LDS_AS void*)(Ald + off), 16, 0, 0);
  }
  __syncthreads();                       // only barrier before epilogue

  const int colw = col0 + w * 64;
  const int cb = tileN * 4 + w;
  f32x4 acc[4][4];
  #pragma unroll
  for (int ct = 0; ct < 4; ++ct)
    #pragma unroll
    for (int rt = 0; rt < 4; ++rt) acc[ct][rt] = {0.f, 0.f, 0.f, 0.f};

  const unsigned char* wpB = Wp + (size_t)cb * 32768 + lane * 16;
  i64x2 bc[2];
  bc[0] = *(const i64x2*)(wpB);
  bc[1] = *(const i64x2*)(wpB + 1024);

  #pragma unroll 4
  for (int ks = 0; ks < 16; ++ks) {
    i64x2 af[2];
    #pragma unroll
    for (int rtp = 0; rtp < 2; ++rtp)
      af[rtp] = *(const i64x2*)&Ald[(ks * 2 + rtp) * 1024 + lane * 16];  // linear b128
    i64x2 bn[2];
    int ks2 = (ks < 15) ? (ks + 1) : 15;   // depth-1 B prefetch
    bn[0] = *(const i64x2*)(wpB + ks2 * 2048);
    bn[1] = *(const i64x2*)(wpB + ks2 * 2048 + 1024);
    #pragma unroll
    for (int ct = 0; ct < 4; ++ct)
      #pragma unroll
      for (int rt = 0; rt < 4; ++rt)
        acc[ct][rt] = __builtin_amdgcn_mfma_f32_16x16x32_fp8_fp8(
            af[rt >> 1][rt & 1], bc[ct >> 1][ct & 1], acc[ct][rt], 0, 0, 0);
    bc[0] = bn[0]; bc[1] = bn[1];
  }

  // epilogue 1: row-wise sum(exp(logit+bias)) -> per-block partial (no atomics)
  // col(ct) = colw + (ct>>1)*32 + (ct&1)*16 + ln15
  // row(rt,r) = row0 + (rt>>1)*32 + (rt&1)*16 + quad*4 + r
  float bvl[4];
  #pragma unroll
  for (int ct = 0; ct < 4; ++ct)
    bvl[ct] = bias[colw + (ct >> 1) * 32 + (ct & 1) * 16 + ln15] * L2E;
  const float SC = 0.0625f * L2E;        // undo W x16 prescale, ln->log2

  #pragma unroll
  for (int rt = 0; rt < 4; ++rt) {
    #pragma unroll
    for (int r = 0; r < 4; ++r) {
      float s = 0.f;
      #pragma unroll
      for (int ct = 0; ct < 4; ++ct) s += fexp2(acc[ct][rt][r] * SC + bvl[ct]);
      s += __shfl_xor(s, 1, 64);
      s += __shfl_xor(s, 2, 64);
      s += __shfl_xor(s, 4, 64);
      s += __shfl_xor(s, 8, 64);
      if (ln15 == 0)
        Spw[w][(rt >> 1) * 32 + (rt & 1) * 16 + quad * 4 + r] = s;
    }
  }
  __syncthreads();
  if (tid < 64) {
    float p = Spw[0][tid] + Spw[1][tid] + Spw[2][tid] + Spw[3][tid];
    Spart[(size_t)tileN * BT + row0 + tid] = p;
  }

  // epilogue 2: beam-column scatter (raw ln-domain logit + bias)
  const int tbase = row0 & 511;
  #pragma unroll
  for (int ct = 0; ct < 4; ++ct) {
    for (int s = 0; s < 31; ++s) {
      int local = selv[s] - colw - (ct >> 1) * 32 - (ct & 1) * 16;
      if (local >= 0 && local < 16 && ln15 == local) {
        float bvs = selb[s];
        #pragma unroll
        for (int rt = 0; rt < 4; ++rt)
          #pragma unroll
          for (int r = 0; r < 4; ++r) {
            int t = tbase + (rt >> 1) * 32 + (rt & 1) * 16 + quad * 4 + r;
            selL[((size_t)bb * Tt + t) * 31 + s] = acc[ct][rt][r] * 0.0625f + bvs;
          }
      }
    }
  }
}

// ---- CTC DP + output assembly, log2 domain. grid: B blocks x 256 threads ----
__global__ __launch_bounds__(256) void kC(const float* __restrict__ selL,
                                          const float* __restrict__ Spart,
                                          const int* __restrict__ xl,
                                          const int* __restrict__ beam,
                                          const int* __restrict__ blankp,
                                          const int* __restrict__ eosp,
                                          float* __restrict__ out,
                                          int Ly, int CB) {
  __shared__ float sl[Tt * 31];     // raw logits * log2(e)
  __shared__ float lgS[Tt];         // log2(sum_exp)
  __shared__ float lastP1[Tt];      // log2-domain blank cumsum
  __shared__ float blankLp[Tt];     // log2-domain blank logp
  const int b = blockIdx.x, tid = threadIdx.x;

  for (int i = tid; i < Tt * 31; i += 256)
    sl[i] = selL[(size_t)b * Tt * 31 + i] * L2E;
  for (int tt = tid; tt < Tt; tt += 256) {
    float s = 0.f;
    #pragma unroll
    for (int n = 0; n < 16; ++n) s += Spart[(size_t)n * BT + b * Tt + tt];
    lgS[tt] = flog2(s);
  }
  __syncthreads();

  float* orow = out + (size_t)b * Vv;
  for (int i = tid; i < Vv; i += 256) orow[i] = LOGZERO;

  const int xlb = xl[b];
  float curP = LOGZERO;
  if (tid < 64) {
    const int lane = tid;
    float vloc[8];
    float run = 0.f;
    #pragma unroll
    for (int u = 0; u < 8; ++u) {
      int t = lane * 8 + u;
      float bl = sl[t * 31] - lgS[t];
      blankLp[t] = bl;
      run += bl;
      vloc[u] = run;
    }
    float inc = run;
    #pragma unroll
    for (int off = 1; off < 64; off <<= 1) {
      float o = __shfl_up(inc, off, 64);
      if (lane >= off) inc += o;
    }
    float excl = inc - run;
    #pragma unroll
    for (int u = 0; u < 8; ++u) lastP1[lane * 8 + u] = vloc[u] + excl;

    const int kk = (lane < CB) ? lane : (CB - 1);
    const float LOG2ZERO = LOGZERO * L2E;
    float Pn = LOG2ZERO, Pb = LOG2ZERO;
    float mrun = -3.0e38f, srun = 0.0f;
    int start = (Ly < Tt - 1) ? Ly : (Tt - 1);
    if (start == 0) {
      Pn = sl[1 + kk] - lgS[0];
      float vv = (0 < xlb) ? lg2add(Pn, Pb) : LOG2ZERO;
      float nm = fmaxf(mrun, vv);
      srun = srun * fexp2(mrun - nm) + fexp2(vv - nm);
      mrun = nm;
    }
    int t0 = (start > 1) ? start : 1;
    #pragma unroll 2
    for (int t = t0; t < Tt; ++t) {
      float xn = sl[t * 31 + 1 + kk] - lgS[t];
      float xb = blankLp[t];
      float pref = lastP1[t - 1];   // lastPsum == lastP1 bit-exactly
      float Pn2 = lg2add(Pn, pref) + xn;
      float Pb2 = lg2add(Pn, Pb) + xb;
      Pn = Pn2; Pb = Pb2;
      float vv = (t < xlb) ? lg2add(Pn, Pb) : LOG2ZERO;   // off critical path
      float nm = fmaxf(mrun, vv);
      srun = srun * fexp2(mrun - nm) + fexp2(vv - nm);
      mrun = nm;
    }
    curP = (mrun + flog2(srun)) * LN2;       // back to ln domain
  }
  __syncthreads();   // LOGZERO fill + lastP1 complete

  if (tid < 64) {
    if (tid < CB) orow[beam[b * CB + tid]] = curP;
  }
  __syncthreads();
  if (tid == 0) {
    float eosv = (xlb >= 1) ? lastP1[xlb - 1] * LN2 : 0.0f;
    orow[*eosp] = eosv;
    orow[*blankp] = LOGZERO;
  }
}

extern "C" void kernel_launch(void* const* d_in, const int* in_sizes, int n_in,
                              void* d_out, int out_size, void* d_ws, size_t ws_size,
                              hipStream_t stream) {
  (void)n_in; (void)out_size; (void)ws_size;
  const float* x    = (const float*)d_in[0];
  const float* W    = (const float*)d_in[1];
  const float* bias = (const float*)d_in[2];
  const int* xl     = (const int*)d_in[3];
  const int* beam   = (const int*)d_in[5];
  const int* blankp = (const int*)d_in[6];
  const int* eosp   = (const int*)d_in[7];
  const int Ly = in_sizes[4] / Bb;
  const int CB = in_sizes[5] / Bb;

  float* Spart = (float*)d_ws;                                            // 1 MB
  float* selL  = (float*)((char*)d_ws + (size_t)0x100000);                // 2.03 MB
  unsigned char* Xfp = (unsigned char*)((char*)d_ws + (size_t)0x400000);  // 8 MB
  unsigned char* Wp  = (unsigned char*)((char*)d_ws + (size_t)0xC00000);  // 2 MB
  float* outf = (float*)d_out;

  kPre<<<2560, 256, 0, stream>>>(x, W, Xfp, Wp);
  kA<<<4096, 256, 0, stream>>>(Xfp, Wp, bias, beam, blankp, Spart, selL, CB);
  kC<<<Bb, 256, 0, stream>>>(selL, Spart, xl, beam, blankp, eosp, outf, Ly, CB);
}

// Round 13
// 221.938 us; speedup vs baseline: 1.9779x; 1.0089x over previous
//
#include <hip/hip_runtime.h>
#include <hip/hip_fp8.h>

#define LOGZERO -4290774016.0f   // -(65504^2), exactly representable in fp32
#define L2E 1.4426950408889634f  // log2(e)
#define LN2 0.6931471805599453f

constexpr int Bb = 32, Tt = 512, Dd = 512, Vv = 4096;
constexpr int BT = Bb * Tt;

typedef __attribute__((ext_vector_type(4))) float f32x4;
typedef __attribute__((ext_vector_type(2))) long i64x2;
typedef long i64;

#define GLOBAL_AS __attribute__((address_space(1)))
#define LDS_AS    __attribute__((address_space(3)))

__device__ __forceinline__ float fexp2(float x) { return __builtin_amdgcn_exp2f(x); }  // 2^x
__device__ __forceinline__ float flog2(float x) { return __builtin_amdgcn_logf(x); }   // log2(x)

// pack 4 floats (scaled) -> 4 OCP e4m3 bytes
__device__ __forceinline__ unsigned cvt4_fp8(float4 v, float s) {
#if __has_builtin(__builtin_amdgcn_cvt_pk_fp8_f32)
  int p = __builtin_amdgcn_cvt_pk_fp8_f32(v.x * s, v.y * s, 0, false);
  p = __builtin_amdgcn_cvt_pk_fp8_f32(v.z * s, v.w * s, p, true);
  return (unsigned)p;
#else
  unsigned b0 = __hip_cvt_float_to_fp8(v.x * s, __HIP_SATFINITE, __HIP_E4M3);
  unsigned b1 = __hip_cvt_float_to_fp8(v.y * s, __HIP_SATFINITE, __HIP_E4M3);
  unsigned b2 = __hip_cvt_float_to_fp8(v.z * s, __HIP_SATFINITE, __HIP_E4M3);
  unsigned b3 = __hip_cvt_float_to_fp8(v.w * s, __HIP_SATFINITE, __HIP_E4M3);
  return b0 | (b1 << 8) | (b2 << 16) | (b3 << 24);
#endif
}

// logaddexp in the log2 domain
__device__ __forceinline__ float lg2add(float a, float b) {
  float mx = fmaxf(a, b);
  float d  = fabsf(a - b);
  return mx + flog2(1.0f + fexp2(-d));
}

// ---- kPre: pack x and W into fp8 FRAGMENT-ORDER layouts ----
// Index remap for coalescing: quad = t&3 fastest -> 4 threads read 128 B
// consecutive; a wave's 64 stores form one contiguous (permuted) 1-KB burst.
// Xfp (per 64-row tileM, 32 KB): slot16 = tM*2048 + (ks*2+rtp)*64 + quad*16 + ln15,
//   bytes = { x[tM*64+rtp*32+ln15][ks*32+quad*8 ..+8], same row +16 }.
// Wp (per cb=64-col block, 32 KB): slot16 = cb*2048 + (ks*2+ctp)*64 + quad*16 + ln15,
//   bytes = { W[cb*64+ctp*32+ln15][ks*32+quad*8 ..+8]*16, same row +16 }.
__global__ __launch_bounds__(256) void kPre(const float* __restrict__ x,
                                            const float* __restrict__ W,
                                            unsigned char* __restrict__ Xfp,
                                            unsigned char* __restrict__ Wp) {
  const int blk = blockIdx.x, tid = threadIdx.x;
  const int t = blk * 256 + tid;
  if (blk < 2048) {                     // Xfp: t = 0..524287
    int quad = t & 3, ln15 = (t >> 2) & 15, rtp = (t >> 6) & 1;
    int ks = (t >> 7) & 15, tM = t >> 11;
    const float* p0 = x + (size_t)(tM * 64 + rtp * 32 + ln15) * Dd + ks * 32 + quad * 8;
    const float* p1 = p0 + 16 * Dd;
    uint4 o;
    o.x = cvt4_fp8(*(const float4*)p0, 1.0f);
    o.y = cvt4_fp8(*(const float4*)(p0 + 4), 1.0f);
    o.z = cvt4_fp8(*(const float4*)p1, 1.0f);
    o.w = cvt4_fp8(*(const float4*)(p1 + 4), 1.0f);
    size_t slot = (size_t)tM * 2048 + (ks * 2 + rtp) * 64 + quad * 16 + ln15;
    *(uint4*)(Xfp + slot * 16) = o;
  } else {                              // Wp: tt = 0..131071
    int tt = t - 2048 * 256;
    int quad = tt & 3, ln15 = (tt >> 2) & 15, ctp = (tt >> 6) & 1;
    int ks = (tt >> 7) & 15, cb = tt >> 11;
    const float* p0 = W + (size_t)(cb * 64 + ctp * 32 + ln15) * Dd + ks * 32 + quad * 8;
    const float* p1 = p0 + 16 * Dd;
    uint4 o;
    o.x = cvt4_fp8(*(const float4*)p0, 16.0f);   // x16 prescale into e4m3 range
    o.y = cvt4_fp8(*(const float4*)(p0 + 4), 16.0f);
    o.z = cvt4_fp8(*(const float4*)p1, 16.0f);
    o.w = cvt4_fp8(*(const float4*)(p1 + 4), 16.0f);
    size_t slot = (size_t)cb * 2048 + (ks * 2 + ctp) * 64 + quad * 16 + ln15;
    *(uint4*)(Wp + slot * 16) = o;
  }
}

// ---- barrier-free fp8 GEMM + exp-sum partials + beam scatter, M_tile=64 ----
// grid 4096, 256 threads (4 waves). Block = 64 rows x 256 cols, full K=512.
// A = 32 KB packed LDS (linear 1KB DMA bursts, conflict-free ds_read_b128);
// B = 2 contiguous dwordx4 loads/k-step, depth-1 prefetch, zero K-loop
// barriers, FULL unroll (compile-time offsets). 4 blocks/CU latency cover.
__global__ __launch_bounds__(256, 4) void kA(const unsigned char* __restrict__ Xfp,
                                             const unsigned char* __restrict__ Wp,
                                             const float* __restrict__ bias,
                                             const int* __restrict__ beam,
                                             const int* __restrict__ blankp,
                                             float* __restrict__ Spart,
                                             float* __restrict__ selL,
                                             int CB) {
  __shared__ unsigned char Ald[32768];   // packed A tile (64 rows x 512 K)
  __shared__ float Spw[4][64];
  __shared__ int   selv[31];
  __shared__ float selb[31];

  const int tid = threadIdx.x;
  const int tileN = blockIdx.x & 15;
  const int tileM = blockIdx.x >> 4;
  const int row0 = tileM * 64, col0 = tileN * 256;
  const int bb = row0 >> 9;              // batch of this block (64 | 512)
  const int lane = tid & 63, w = tid >> 6;
  const int ln15 = lane & 15, quad = lane >> 4;

  if (tid < 31) {
    int v = (tid == 0) ? *blankp : beam[bb * CB + tid - 1];
    selv[tid] = v;
    selb[tid] = bias[v];
  }

  // stage packed A tile: 32 x 1KB fully-linear DMA bursts (wave w does 8)
  const unsigned char* src = Xfp + (size_t)tileM * 32768;
  #pragma unroll
  for (int i = 0; i < 8; ++i) {
    int off = (w * 8 + i) * 1024;
    __builtin_amdgcn_global_load_lds((const GLOBAL_AS void*)(src + off + lane * 16),
                                     (LDS_AS void*)(Ald + off), 16, 0, 0);
  }
  __syncthreads();                       // only barrier before epilogue

  const int colw = col0 + w * 64;
  const int cb = tileN * 4 + w;
  f32x4 acc[4][4];
  #pragma unroll
  for (int ct = 0; ct < 4; ++ct)
    #pragma unroll
    for (int rt = 0; rt < 4; ++rt) acc[ct][rt] = {0.f, 0.f, 0.f, 0.f};

  const unsigned char* wpB = Wp + (size_t)cb * 32768 + lane * 16;
  i64x2 bc[2];
  bc[0] = *(const i64x2*)(wpB);
  bc[1] = *(const i64x2*)(wpB + 1024);

  #pragma unroll
  for (int ks = 0; ks < 16; ++ks) {
    i64x2 af[2];
    #pragma unroll
    for (int rtp = 0; rtp < 2; ++rtp)
      af[rtp] = *(const i64x2*)&Ald[(ks * 2 + rtp) * 1024 + lane * 16];  // linear b128
    i64x2 bn[2];
    int ks2 = (ks < 15) ? (ks + 1) : 15;   // depth-1 B prefetch
    bn[0] = *(const i64x2*)(wpB + ks2 * 2048);
    bn[1] = *(const i64x2*)(wpB + ks2 * 2048 + 1024);
    #pragma unroll
    for (int ct = 0; ct < 4; ++ct)
      #pragma unroll
      for (int rt = 0; rt < 4; ++rt)
        acc[ct][rt] = __builtin_amdgcn_mfma_f32_16x16x32_fp8_fp8(
            af[rt >> 1][rt & 1], bc[ct >> 1][ct & 1], acc[ct][rt], 0, 0, 0);
    bc[0] = bn[0]; bc[1] = bn[1];
  }

  // epilogue 1: row-wise sum(exp(logit+bias)) -> per-block partial (no atomics)
  // col(ct) = colw + (ct>>1)*32 + (ct&1)*16 + ln15
  // row(rt,r) = row0 + (rt>>1)*32 + (rt&1)*16 + quad*4 + r
  float bvl[4];
  #pragma unroll
  for (int ct = 0; ct < 4; ++ct)
    bvl[ct] = bias[colw + (ct >> 1) * 32 + (ct & 1) * 16 + ln15] * L2E;
  const float SC = 0.0625f * L2E;        // undo W x16 prescale, ln->log2

  #pragma unroll
  for (int rt = 0; rt < 4; ++rt) {
    #pragma unroll
    for (int r = 0; r < 4; ++r) {
      float s = 0.f;
      #pragma unroll
      for (int ct = 0; ct < 4; ++ct) s += fexp2(acc[ct][rt][r] * SC + bvl[ct]);
      s += __shfl_xor(s, 1, 64);
      s += __shfl_xor(s, 2, 64);
      s += __shfl_xor(s, 4, 64);
      s += __shfl_xor(s, 8, 64);
      if (ln15 == 0)
        Spw[w][(rt >> 1) * 32 + (rt & 1) * 16 + quad * 4 + r] = s;
    }
  }
  __syncthreads();
  if (tid < 64) {
    float p = Spw[0][tid] + Spw[1][tid] + Spw[2][tid] + Spw[3][tid];
    Spart[(size_t)tileN * BT + row0 + tid] = p;
  }

  // epilogue 2: beam-column scatter (raw ln-domain logit + bias)
  const int tbase = row0 & 511;
  #pragma unroll
  for (int ct = 0; ct < 4; ++ct) {
    for (int s = 0; s < 31; ++s) {
      int local = selv[s] - colw - (ct >> 1) * 32 - (ct & 1) * 16;
      if (local >= 0 && local < 16 && ln15 == local) {
        float bvs = selb[s];
        #pragma unroll
        for (int rt = 0; rt < 4; ++rt)
          #pragma unroll
          for (int r = 0; r < 4; ++r) {
            int t = tbase + (rt >> 1) * 32 + (rt & 1) * 16 + quad * 4 + r;
            selL[((size_t)bb * Tt + t) * 31 + s] = acc[ct][rt][r] * 0.0625f + bvs;
          }
      }
    }
  }
}

// ---- CTC DP + output assembly, log2 domain. grid: B blocks x 256 threads ----
__global__ __launch_bounds__(256) void kC(const float* __restrict__ selL,
                                          const float* __restrict__ Spart,
                                          const int* __restrict__ xl,
                                          const int* __restrict__ beam,
                                          const int* __restrict__ blankp,
                                          const int* __restrict__ eosp,
                                          float* __restrict__ out,
                                          int Ly, int CB) {
  __shared__ float sl[Tt * 31];     // raw logits * log2(e)
  __shared__ float lgS[Tt];         // log2(sum_exp)
  __shared__ float lastP1[Tt];      // log2-domain blank cumsum
  __shared__ float blankLp[Tt];     // log2-domain blank logp
  const int b = blockIdx.x, tid = threadIdx.x;

  for (int i = tid; i < Tt * 31; i += 256)
    sl[i] = selL[(size_t)b * Tt * 31 + i] * L2E;
  for (int tt = tid; tt < Tt; tt += 256) {
    float s = 0.f;
    #pragma unroll
    for (int n = 0; n < 16; ++n) s += Spart[(size_t)n * BT + b * Tt + tt];
    lgS[tt] = flog2(s);
  }
  __syncthreads();

  float* orow = out + (size_t)b * Vv;
  for (int i = tid; i < Vv; i += 256) orow[i] = LOGZERO;

  const int xlb = xl[b];
  float curP = LOGZERO;
  if (tid < 64) {
    const int lane = tid;
    float vloc[8];
    float run = 0.f;
    #pragma unroll
    for (int u = 0; u < 8; ++u) {
      int t = lane * 8 + u;
      float bl = sl[t * 31] - lgS[t];
      blankLp[t] = bl;
      run += bl;
      vloc[u] = run;
    }
    float inc = run;
    #pragma unroll
    for (int off = 1; off < 64; off <<= 1) {
      float o = __shfl_up(inc, off, 64);
      if (lane >= off) inc += o;
    }
    float excl = inc - run;
    #pragma unroll
    for (int u = 0; u < 8; ++u) lastP1[lane * 8 + u] = vloc[u] + excl;

    const int kk = (lane < CB) ? lane : (CB - 1);
    const float LOG2ZERO = LOGZERO * L2E;
    float Pn = LOG2ZERO, Pb = LOG2ZERO;
    float mrun = -3.0e38f, srun = 0.0f;
    int start = (Ly < Tt - 1) ? Ly : (Tt - 1);
    if (start == 0) {
      Pn = sl[1 + kk] - lgS[0];
      float vv = (0 < xlb) ? lg2add(Pn, Pb) : LOG2ZERO;
      float nm = fmaxf(mrun, vv);
      srun = srun * fexp2(mrun - nm) + fexp2(vv - nm);
      mrun = nm;
    }
    int t0 = (start > 1) ? start : 1;
    #pragma unroll 2
    for (int t = t0; t < Tt; ++t) {
      float xn = sl[t * 31 + 1 + kk] - lgS[t];
      float xb = blankLp[t];
      float pref = lastP1[t - 1];   // lastPsum == lastP1 bit-exactly
      float Pn2 = lg2add(Pn, pref) + xn;
      float Pb2 = lg2add(Pn, Pb) + xb;
      Pn = Pn2; Pb = Pb2;
      float vv = (t < xlb) ? lg2add(Pn, Pb) : LOG2ZERO;   // off critical path
      float nm = fmaxf(mrun, vv);
      srun = srun * fexp2(mrun - nm) + fexp2(vv - nm);
      mrun = nm;
    }
    curP = (mrun + flog2(srun)) * LN2;       // back to ln domain
  }
  __syncthreads();   // LOGZERO fill + lastP1 complete

  if (tid < 64) {
    if (tid < CB) orow[beam[b * CB + tid]] = curP;
  }
  __syncthreads();
  if (tid == 0) {
    float eosv = (xlb >= 1) ? lastP1[xlb - 1] * LN2 : 0.0f;
    orow[*eosp] = eosv;
    orow[*blankp] = LOGZERO;
  }
}

extern "C" void kernel_launch(void* const* d_in, const int* in_sizes, int n_in,
                              void* d_out, int out_size, void* d_ws, size_t ws_size,
                              hipStream_t stream) {
  (void)n_in; (void)out_size; (void)ws_size;
  const float* x    = (const float*)d_in[0];
  const float* W    = (const float*)d_in[1];
  const float* bias = (const float*)d_in[2];
  const int* xl     = (const int*)d_in[3];
  const int* beam   = (const int*)d_in[5];
  const int* blankp = (const int*)d_in[6];
  const int* eosp   = (const int*)d_in[7];
  const int Ly = in_sizes[4] / Bb;
  const int CB = in_sizes[5] / Bb;

  float* Spart = (float*)d_ws;                                            // 1 MB
  float* selL  = (float*)((char*)d_ws + (size_t)0x100000);                // 2.03 MB
  unsigned char* Xfp = (unsigned char*)((char*)d_ws + (size_t)0x400000);  // 8 MB
  unsigned char* Wp  = (unsigned char*)((char*)d_ws + (size_t)0xC00000);  // 2 MB
  float* outf = (float*)d_out;

  kPre<<<2560, 256, 0, stream>>>(x, W, Xfp, Wp);
  kA<<<4096, 256, 0, stream>>>(Xfp, Wp, bias, beam, blankp, Spart, selL, CB);
  kC<<<Bb, 256, 0, stream>>>(selL, Spart, xl, beam, blankp, eosp, outf, Ly, CB);
}